// Round 1
// baseline (902.655 us; speedup 1.0000x reference)
//
#include <hip/hip_runtime.h>
#include <math.h>

// Problem constants
#define NROWS 32768   // B*H*W
#define KCB   1024    // num embeddings
#define DDIM  256     // embedding dim

// Output offsets (in floats)
#define O_LOSS 0
#define O_Q    1
#define O_PERP 8388609
#define O_ENC  8388610
#define O_NCNT 41943042
#define O_EMAW 41944066
#define O_EMB  42206210

// Workspace offsets (in floats)
#define W_WSQ  0        // 1024
#define W_XSQ  1024     // 32768
#define W_IDX  33792    // 32768 (int)
#define W_COL  66560    // 1024
#define W_HCNT 67584    // 1024
#define W_BENT 68608    // 8192
#define W_DW   76800    // 262144
#define W_NCNT 338944   // 1024
#define W_WT   339968   // 262144 (W transposed [D][K])
// total 602112 floats = 2.41 MB

__device__ __forceinline__ float wred_sum(float v) {
#pragma unroll
  for (int off = 32; off > 0; off >>= 1) v += __shfl_xor(v, off);
  return v;
}

// ---------------- init: zero accumulators ----------------
__global__ void k_init(float* __restrict__ colsum, float* __restrict__ hcnt,
                       float* __restrict__ dw) {
  int i = blockIdx.x * 256 + threadIdx.x;
  if (i < 1024) { colsum[i] = 0.f; hcnt[i] = 0.f; }
  if (i < 262144) dw[i] = 0.f;
}

// ---------------- |w_k|^2 and W^T ----------------
__global__ void k_wsqT(const float* __restrict__ w, float* __restrict__ wsq,
                       float* __restrict__ wT) {
  int t = threadIdx.x;
  int lane = t & 63, wv = t >> 6;
  int k = blockIdx.x * 4 + wv;
  float4 v = *(const float4*)&w[(size_t)k * DDIM + lane * 4];
  float s = v.x * v.x + v.y * v.y + v.z * v.z + v.w * v.w;
  s = wred_sum(s);
  if (lane == 0) wsq[k] = s;
  int d = lane * 4;
  wT[(size_t)(d + 0) * KCB + k] = v.x;
  wT[(size_t)(d + 1) * KCB + k] = v.y;
  wT[(size_t)(d + 2) * KCB + k] = v.z;
  wT[(size_t)(d + 3) * KCB + k] = v.w;
}

// ---------------- |x_n|^2 ----------------
__global__ void k_xsq(const float* __restrict__ x, float* __restrict__ xsq) {
  int n = blockIdx.x * 256 + threadIdx.x;
  int b = n >> 10, m = n & 1023;
  const float* p = x + (size_t)b * DDIM * 1024 + m;
  float s = 0.f;
#pragma unroll 4
  for (int d = 0; d < DDIM; ++d) { float v = p[(size_t)d * 1024]; s = fmaf(v, v, s); }
  xsq[n] = s;
}

// ---------------- GEMM1: S[n,k] = x_n . w_k  -> E region ----------------
// tile 128(n) x 128(k), inner D in chunks of 16, 256 threads, 8x8 micro
__global__ __launch_bounds__(256) void k_gemm1(const float* __restrict__ x,
                                               const float* __restrict__ wT,
                                               float* __restrict__ E /*8B aligned*/) {
  __shared__ float xt[16 * 128];
  __shared__ float wt[16 * 128];
  int t = threadIdx.x;
  int k0 = blockIdx.x * 128;
  int n0 = blockIdx.y * 128;
  int b = n0 >> 10, m0 = n0 & 1023;
  int tr = t >> 4, tc = t & 15;
  float acc[8][8] = {};
  for (int dk0 = 0; dk0 < DDIM; dk0 += 16) {
#pragma unroll
    for (int p = 0; p < 2; ++p) {
      int dl = p * 8 + (t >> 5);
      int ml = (t & 31) * 4;
      float4 v = *(const float4*)&x[(size_t)(b * DDIM + dk0 + dl) * 1024 + m0 + ml];
      *(float4*)&xt[dl * 128 + ml] = v;
    }
#pragma unroll
    for (int p = 0; p < 2; ++p) {
      int dl = p * 8 + (t >> 5);
      int kl = (t & 31) * 4;
      float4 v = *(const float4*)&wT[(size_t)(dk0 + dl) * KCB + k0 + kl];
      *(float4*)&wt[dl * 128 + kl] = v;
    }
    __syncthreads();
#pragma unroll
    for (int dd = 0; dd < 16; ++dd) {
      float a[8], bb[8];
      *(float4*)&a[0] = *(float4*)&xt[dd * 128 + tr * 8];
      *(float4*)&a[4] = *(float4*)&xt[dd * 128 + tr * 8 + 4];
      *(float4*)&bb[0] = *(float4*)&wt[dd * 128 + tc * 8];
      *(float4*)&bb[4] = *(float4*)&wt[dd * 128 + tc * 8 + 4];
#pragma unroll
      for (int i = 0; i < 8; ++i)
#pragma unroll
        for (int j = 0; j < 8; ++j) acc[i][j] = fmaf(a[i], bb[j], acc[i][j]);
    }
    __syncthreads();
  }
  float2* E2 = (float2*)E;
#pragma unroll
  for (int i = 0; i < 8; ++i) {
    size_t base = ((size_t)(n0 + tr * 8 + i) * KCB + k0 + tc * 8) >> 1;
#pragma unroll
    for (int j = 0; j < 4; ++j) {
      float2 v = {acc[i][2 * j], acc[i][2 * j + 1]};
      E2[base + j] = v;
    }
  }
}

// ---------------- row ops: softmax (in place), argmax w/ gumbel ----------------
__global__ __launch_bounds__(256) void k_rowops(float* __restrict__ E /*S in, soft out*/,
                                                const float* __restrict__ G,
                                                const float* __restrict__ wsq,
                                                const float* __restrict__ xsq,
                                                int* __restrict__ idxArr,
                                                float* __restrict__ hcnt,
                                                float* __restrict__ bent) {
  int t = threadIdx.x;
  int lane = t & 63, wv = t >> 6;
  int n = blockIdx.x * 4 + wv;
  size_t rb = (size_t)n * KCB;
  float xs = xsq[n];
  const float2* E2 = (const float2*)E;
  float lsm[16];
  float bv = -3.0e38f; int bi = 0;
  float mm = -3.0e38f;
#pragma unroll
  for (int j = 0; j < 4; ++j) {
    int k = j * 256 + lane * 4;
    float2 sA = E2[(rb + k) >> 1];
    float2 sB = E2[((rb + k) >> 1) + 1];
    float4 w4 = *(const float4*)&wsq[k];
    float4 g4 = *(const float4*)&G[rb + k];
    float sv[4] = {sA.x, sA.y, sB.x, sB.y};
    float wq[4] = {w4.x, w4.y, w4.z, w4.w};
    float gv[4] = {g4.x, g4.y, g4.z, g4.w};
#pragma unroll
    for (int q = 0; q < 4; ++q) {
      float d = (xs + wq[q]) - 2.0f * sv[q];   // distances, same grid as ref
      float nd = -d;
      float l = nd * 2.0f;                      // -d/TAU, TAU=0.5
      lsm[j * 4 + q] = l;
      mm = fmaxf(mm, l);
      float sc = nd + gv[q];                    // -dist + gumbel (fp32 rounding mimics ref)
      int kk = k + q;
      if (sc > bv) { bv = sc; bi = kk; }
    }
  }
#pragma unroll
  for (int off = 1; off < 64; off <<= 1) mm = fmaxf(mm, __shfl_xor(mm, off));
#pragma unroll
  for (int off = 1; off < 64; off <<= 1) {
    float ov = __shfl_xor(bv, off);
    int oi = __shfl_xor(bi, off);
    if (ov > bv || (ov == bv && oi < bi)) { bv = ov; bi = oi; }
  }
  float e[16];
  float ps = 0.f;
#pragma unroll
  for (int u = 0; u < 16; ++u) { e[u] = expf(lsm[u] - mm); ps += e[u]; }
  ps = wred_sum(ps);
  float2* E2w = (float2*)E;
  float ent = 0.f;
#pragma unroll
  for (int j = 0; j < 4; ++j) {
    int k = j * 256 + lane * 4;
    float sf[4];
#pragma unroll
    for (int q = 0; q < 4; ++q) {
      float s = e[j * 4 + q] / ps;
      sf[q] = s;
      ent += s * logf(fmaxf(s, 1e-8f));
    }
    float2 vA = {sf[0], sf[1]}, vB = {sf[2], sf[3]};
    E2w[(rb + k) >> 1] = vA;
    E2w[((rb + k) >> 1) + 1] = vB;
  }
  ent = wred_sum(ent);
  if (lane == 0) {
    idxArr[n] = bi;
    atomicAdd(&hcnt[bi], 1.0f);
  }
  __shared__ float went[4];
  if (lane == 0) went[wv] = ent;
  __syncthreads();
  if (t == 0) bent[blockIdx.x] = went[0] + went[1] + went[2] + went[3];
}

// ---------------- quantized output: out[b,d,h,w] = w[idx[n], d] ----------------
__global__ void k_quant(const float* __restrict__ w, const int* __restrict__ idxArr,
                        float* __restrict__ outQ) {
  int n = blockIdx.x * 256 + threadIdx.x;
  int b = n >> 10, m = n & 1023;
  int id = idxArr[n];
  const float* wr = w + (size_t)id * DDIM;
  float* o = outQ + (size_t)b * DDIM * 1024 + m;
#pragma unroll 4
  for (int d = 0; d < DDIM; ++d) o[(size_t)d * 1024] = wr[d];
}

// ---------------- GEMM2: dw[k,d] += soft^T x ; colsum[k] += soft colsums ----------------
// blocks: 8 ktiles x 2 dtiles x 32 nsplits = 512; tile 128(k) x 128(d), NT=16
__global__ __launch_bounds__(256) void k_gemm2(const float* __restrict__ E /*soft*/,
                                               const float* __restrict__ x,
                                               float* __restrict__ dw,
                                               float* __restrict__ colsum) {
  __shared__ float sl[16 * 128];
  __shared__ float xl[16 * 128];
  int t = threadIdx.x;
  int bid = blockIdx.x;
  int kt = bid & 7, dt = (bid >> 3) & 1, ns = bid >> 4;
  int k0 = kt * 128, d0 = dt * 128;
  int tr = t >> 4, tc = t & 15;
  const float2* E2 = (const float2*)E;
  float acc[8][8] = {};
  float colacc[8] = {};
  for (int s = 0; s < 64; ++s) {
    int nb = ns * 1024 + s * 16;
    int b = nb >> 10, m0 = nb & 1023;
#pragma unroll
    for (int p = 0; p < 2; ++p) {
      int nn = p * 8 + (t >> 5);
      int kl = (t & 31) * 4;
      size_t e0 = ((size_t)(nb + nn) * KCB + k0 + kl) >> 1;
      float2 vA = E2[e0], vB = E2[e0 + 1];
      float4 v = {vA.x, vA.y, vB.x, vB.y};
      *(float4*)&sl[nn * 128 + kl] = v;
    }
#pragma unroll
    for (int p = 0; p < 2; ++p) {
      int u = p * 256 + t;
      int d = u >> 2, nseg = u & 3;
      float4 v = *(const float4*)&x[(size_t)(b * DDIM + d0 + d) * 1024 + m0 + nseg * 4];
      xl[(nseg * 4 + 0) * 128 + d] = v.x;
      xl[(nseg * 4 + 1) * 128 + d] = v.y;
      xl[(nseg * 4 + 2) * 128 + d] = v.z;
      xl[(nseg * 4 + 3) * 128 + d] = v.w;
    }
    __syncthreads();
#pragma unroll
    for (int nn = 0; nn < 16; ++nn) {
      float a[8], bb[8];
      *(float4*)&a[0] = *(float4*)&sl[nn * 128 + tr * 8];
      *(float4*)&a[4] = *(float4*)&sl[nn * 128 + tr * 8 + 4];
      *(float4*)&bb[0] = *(float4*)&xl[nn * 128 + tc * 8];
      *(float4*)&bb[4] = *(float4*)&xl[nn * 128 + tc * 8 + 4];
#pragma unroll
      for (int i = 0; i < 8; ++i)
#pragma unroll
        for (int j = 0; j < 8; ++j) acc[i][j] = fmaf(a[i], bb[j], acc[i][j]);
      if (dt == 0 && tc == 0) {
#pragma unroll
        for (int i = 0; i < 8; ++i) colacc[i] += a[i];
      }
    }
    __syncthreads();
  }
#pragma unroll
  for (int i = 0; i < 8; ++i)
#pragma unroll
    for (int j = 0; j < 8; ++j)
      atomicAdd(&dw[(size_t)(k0 + tr * 8 + i) * DDIM + d0 + tc * 8 + j], acc[i][j]);
  if (dt == 0 && tc == 0) {
#pragma unroll
    for (int i = 0; i < 8; ++i) atomicAdd(&colsum[k0 + tr * 8 + i], colacc[i]);
  }
}

// ---------------- finalize scalars, new_count ----------------
__global__ void k_final1(const float* __restrict__ ema_count, const float* __restrict__ colsum,
                         const float* __restrict__ hcnt, const float* __restrict__ bent,
                         float* __restrict__ ncnt, float* __restrict__ out) {
  __shared__ float red[1024];
  int t = threadIdx.x;
  const float onem = 1.0f - 0.99f;
  float nc = ema_count[t] * 0.99f + colsum[t] * onem;
  nc = (nc + 1e-5f) / (32768.0f + 1024.0f * 1e-5f) * 32768.0f;
  out[O_NCNT + t] = nc;
  ncnt[t] = nc;
  float s = 0.f;
  for (int i = t; i < 8192; i += 1024) s += bent[i];
  red[t] = s;
  __syncthreads();
  for (int off = 512; off > 0; off >>= 1) { if (t < off) red[t] += red[t + off]; __syncthreads(); }
  if (t == 0) out[O_LOSS] = 0.25f * (red[0] / 32768.0f);
  __syncthreads();
  float avg = hcnt[t] * (1.0f / 32768.0f);
  red[t] = avg * logf(avg + 1e-10f);
  __syncthreads();
  for (int off = 512; off > 0; off >>= 1) { if (t < off) red[t] += red[t + off]; __syncthreads(); }
  if (t == 0) out[O_PERP] = expf(-red[0]);
}

// ---------------- one-hot encodings (overwrites soft) ----------------
__global__ void k_onehot(const int* __restrict__ idxArr, float* __restrict__ E) {
  int gid = blockIdx.x * 256 + threadIdx.x;
  int n = gid >> 8;
  int k4 = (gid & 255) * 4;
  int id = idxArr[n];
  float2* E2 = (float2*)E;
  size_t base = ((size_t)n * KCB + k4) >> 1;
  float2 vA = {(float)(k4 == id), (float)(k4 + 1 == id)};
  float2 vB = {(float)(k4 + 2 == id), (float)(k4 + 3 == id)};
  E2[base] = vA;
  E2[base + 1] = vB;
}

// ---------------- new_ema_weight & new_embedding ----------------
__global__ void k_final2(const float* __restrict__ ema_w, const float* __restrict__ dw,
                         const float* __restrict__ ncnt, float* __restrict__ outEW,
                         float* __restrict__ outEMB) {
  int i = blockIdx.x * 256 + threadIdx.x;
  int k = i >> 8;
  const float onem = 1.0f - 0.99f;
  float ew = ema_w[i] * 0.99f + dw[i] * onem;
  outEW[i] = ew;
  outEMB[i] = ew / ncnt[k];
}

extern "C" void kernel_launch(void* const* d_in, const int* in_sizes, int n_in,
                              void* d_out, int out_size, void* d_ws, size_t ws_size,
                              hipStream_t stream) {
  const float* x = (const float*)d_in[0];
  const float* w = (const float*)d_in[1];
  const float* ema_count = (const float*)d_in[2];
  const float* ema_w = (const float*)d_in[3];
  const float* g = (const float*)d_in[4];
  float* out = (float*)d_out;
  float* ws = (float*)d_ws;

  float* wsq    = ws + W_WSQ;
  float* xsq    = ws + W_XSQ;
  int*   idxArr = (int*)(ws + W_IDX);
  float* colsum = ws + W_COL;
  float* hcnt   = ws + W_HCNT;
  float* bent   = ws + W_BENT;
  float* dw     = ws + W_DW;
  float* ncnt   = ws + W_NCNT;
  float* wT     = ws + W_WT;

  float* outQ = out + O_Q;
  float* outE = out + O_ENC;

  k_init<<<1024, 256, 0, stream>>>(colsum, hcnt, dw);
  k_wsqT<<<256, 256, 0, stream>>>(w, wsq, wT);
  k_xsq<<<128, 256, 0, stream>>>(x, xsq);
  k_gemm1<<<dim3(8, 256), 256, 0, stream>>>(x, wT, outE);
  k_rowops<<<8192, 256, 0, stream>>>(outE, g, wsq, xsq, idxArr, hcnt, bent);
  k_quant<<<128, 256, 0, stream>>>(w, idxArr, outQ);
  k_gemm2<<<512, 256, 0, stream>>>(outE, x, dw, colsum);
  k_final1<<<1, 1024, 0, stream>>>(ema_count, colsum, hcnt, bent, ncnt, out);
  k_onehot<<<32768, 256, 0, stream>>>(idxArr, outE);
  k_final2<<<1024, 256, 0, stream>>>(ema_w, dw, ncnt, out + O_EMAW, out + O_EMB);
}

// Round 2
// 454.246 us; speedup vs baseline: 1.9871x; 1.9871x over previous
//
#include <hip/hip_runtime.h>
#include <math.h>

// Problem constants
#define NROWS 32768   // B*H*W
#define KCB   1024    // num embeddings
#define DDIM  256     // embedding dim

// Output offsets (in floats)
#define O_LOSS 0
#define O_Q    1
#define O_PERP 8388609
#define O_ENC  8388610
#define O_NCNT 41943042
#define O_EMAW 41944066
#define O_EMB  42206210

// E-region scratch layout (in floats, relative to outE; region = 33554432 floats)
#define E_STBF   0         // STbf bf16 [1024][32768] = 33554432 ushort = 16777216 floats
#define E_XBF    16777216  // xbf bf16 [32][256][1024] = 8388608 ushort = 4194304 floats
#define E_PART   20971520  // dw partials [32][1024][256] fp32 = 8388608 floats (ends 29360128)

// Workspace offsets (in floats)
#define W_WSQ  0        // 1024
#define W_XSQ  1024     // 32768
#define W_IDX  33792    // 32768 (int)
#define W_COL  66560    // 1024
#define W_HCNT 67584    // 1024
#define W_BENT 68608    // 8192
#define W_NCNT 76800    // 1024
#define W_WT   77824    // 262144 (W transposed [D][K])
// total ~340K floats = 1.36 MB

typedef __attribute__((ext_vector_type(8))) short bf16x8;
typedef __attribute__((ext_vector_type(4))) float f32x4;

__device__ __forceinline__ float wred_sum(float v) {
#pragma unroll
  for (int off = 32; off > 0; off >>= 1) v += __shfl_xor(v, off);
  return v;
}

__device__ __forceinline__ ushort f2bf(float f) {
  union { float f; unsigned u; } c; c.f = f;
  unsigned u = c.u;
  return (ushort)((u + 0x7fffu + ((u >> 16) & 1u)) >> 16);  // RNE
}
__device__ __forceinline__ float bf2f(ushort h) {
  union { unsigned u; float f; } c; c.u = ((unsigned)h) << 16;
  return c.f;
}

// ---------------- init: zero hcnt ----------------
__global__ void k_init(float* __restrict__ hcnt) {
  int i = blockIdx.x * 256 + threadIdx.x;
  if (i < 1024) hcnt[i] = 0.f;
}

// ---------------- |w_k|^2 and W^T ----------------
__global__ void k_wsqT(const float* __restrict__ w, float* __restrict__ wsq,
                       float* __restrict__ wT) {
  int t = threadIdx.x;
  int lane = t & 63, wv = t >> 6;
  int k = blockIdx.x * 4 + wv;
  float4 v = *(const float4*)&w[(size_t)k * DDIM + lane * 4];
  float s = v.x * v.x + v.y * v.y + v.z * v.z + v.w * v.w;
  s = wred_sum(s);
  if (lane == 0) wsq[k] = s;
  int d = lane * 4;
  wT[(size_t)(d + 0) * KCB + k] = v.x;
  wT[(size_t)(d + 1) * KCB + k] = v.y;
  wT[(size_t)(d + 2) * KCB + k] = v.z;
  wT[(size_t)(d + 3) * KCB + k] = v.w;
}

// ---------------- |x_n|^2 ----------------
__global__ void k_xsq(const float* __restrict__ x, float* __restrict__ xsq) {
  int n = blockIdx.x * 256 + threadIdx.x;
  int b = n >> 10, m = n & 1023;
  const float* p = x + (size_t)b * DDIM * 1024 + m;
  float s = 0.f;
#pragma unroll 4
  for (int d = 0; d < DDIM; ++d) { float v = p[(size_t)d * 1024]; s = fmaf(v, v, s); }
  xsq[n] = s;
}

// ---------------- GEMM1: S[n,k] = x_n . w_k  -> E region (fp32) ----------------
__global__ __launch_bounds__(256) void k_gemm1(const float* __restrict__ x,
                                               const float* __restrict__ wT,
                                               float* __restrict__ E /*8B aligned*/) {
  __shared__ float xt[16 * 128];
  __shared__ float wt[16 * 128];
  int t = threadIdx.x;
  int k0 = blockIdx.x * 128;
  int n0 = blockIdx.y * 128;
  int b = n0 >> 10, m0 = n0 & 1023;
  int tr = t >> 4, tc = t & 15;
  float acc[8][8] = {};
  for (int dk0 = 0; dk0 < DDIM; dk0 += 16) {
#pragma unroll
    for (int p = 0; p < 2; ++p) {
      int dl = p * 8 + (t >> 5);
      int ml = (t & 31) * 4;
      float4 v = *(const float4*)&x[(size_t)(b * DDIM + dk0 + dl) * 1024 + m0 + ml];
      *(float4*)&xt[dl * 128 + ml] = v;
    }
#pragma unroll
    for (int p = 0; p < 2; ++p) {
      int dl = p * 8 + (t >> 5);
      int kl = (t & 31) * 4;
      float4 v = *(const float4*)&wT[(size_t)(dk0 + dl) * KCB + k0 + kl];
      *(float4*)&wt[dl * 128 + kl] = v;
    }
    __syncthreads();
#pragma unroll
    for (int dd = 0; dd < 16; ++dd) {
      float a[8], bb[8];
      *(float4*)&a[0] = *(float4*)&xt[dd * 128 + tr * 8];
      *(float4*)&a[4] = *(float4*)&xt[dd * 128 + tr * 8 + 4];
      *(float4*)&bb[0] = *(float4*)&wt[dd * 128 + tc * 8];
      *(float4*)&bb[4] = *(float4*)&wt[dd * 128 + tc * 8 + 4];
#pragma unroll
      for (int i = 0; i < 8; ++i)
#pragma unroll
        for (int j = 0; j < 8; ++j) acc[i][j] = fmaf(a[i], bb[j], acc[i][j]);
    }
    __syncthreads();
  }
  float2* E2 = (float2*)E;
#pragma unroll
  for (int i = 0; i < 8; ++i) {
    size_t base = ((size_t)(n0 + tr * 8 + i) * KCB + k0 + tc * 8) >> 1;
#pragma unroll
    for (int j = 0; j < 4; ++j) {
      float2 v = {acc[i][2 * j], acc[i][2 * j + 1]};
      E2[base + j] = v;
    }
  }
}

// ---------------- row ops: softmax -> sbf (bf16, Q region), argmax, entropy ----------------
__global__ __launch_bounds__(256) void k_rowops(const float* __restrict__ E /*S fp32*/,
                                                const float* __restrict__ G,
                                                const float* __restrict__ wsq,
                                                const float* __restrict__ xsq,
                                                int* __restrict__ idxArr,
                                                float* __restrict__ hcnt,
                                                float* __restrict__ bent,
                                                ushort* __restrict__ sbf) {
  int t = threadIdx.x;
  int lane = t & 63, wv = t >> 6;
  int n = blockIdx.x * 4 + wv;
  size_t rb = (size_t)n * KCB;
  float xs = xsq[n];
  const float2* E2 = (const float2*)E;
  float lsm[16];
  float bv = -3.0e38f; int bi = 0;
  float mm = -3.0e38f;
#pragma unroll
  for (int j = 0; j < 4; ++j) {
    int k = j * 256 + lane * 4;
    float2 sA = E2[(rb + k) >> 1];
    float2 sB = E2[((rb + k) >> 1) + 1];
    float4 w4 = *(const float4*)&wsq[k];
    float4 g4 = *(const float4*)&G[rb + k];
    float sv[4] = {sA.x, sA.y, sB.x, sB.y};
    float wq[4] = {w4.x, w4.y, w4.z, w4.w};
    float gv[4] = {g4.x, g4.y, g4.z, g4.w};
#pragma unroll
    for (int q = 0; q < 4; ++q) {
      float d = (xs + wq[q]) - 2.0f * sv[q];
      float nd = -d;
      float l = nd * 2.0f;                      // -d/TAU, TAU=0.5
      lsm[j * 4 + q] = l;
      mm = fmaxf(mm, l);
      float sc = nd + gv[q];
      int kk = k + q;
      if (sc > bv) { bv = sc; bi = kk; }
    }
  }
#pragma unroll
  for (int off = 1; off < 64; off <<= 1) mm = fmaxf(mm, __shfl_xor(mm, off));
#pragma unroll
  for (int off = 1; off < 64; off <<= 1) {
    float ov = __shfl_xor(bv, off);
    int oi = __shfl_xor(bi, off);
    if (ov > bv || (ov == bv && oi < bi)) { bv = ov; bi = oi; }
  }
  float e[16];
  float ps = 0.f;
#pragma unroll
  for (int u = 0; u < 16; ++u) { e[u] = expf(lsm[u] - mm); ps += e[u]; }
  ps = wred_sum(ps);
  ushort* Sb = sbf + rb;
  float ent = 0.f;
#pragma unroll
  for (int j = 0; j < 4; ++j) {
    int k = j * 256 + lane * 4;
    float sf[4];
#pragma unroll
    for (int q = 0; q < 4; ++q) {
      float s = e[j * 4 + q] / ps;
      sf[q] = s;
      ent += s * logf(fmaxf(s, 1e-8f));
    }
    ushort4 o;
    o.x = f2bf(sf[0]); o.y = f2bf(sf[1]); o.z = f2bf(sf[2]); o.w = f2bf(sf[3]);
    *(ushort4*)&Sb[k] = o;
  }
  ent = wred_sum(ent);
  if (lane == 0) {
    idxArr[n] = bi;
    atomicAdd(&hcnt[bi], 1.0f);
  }
  __shared__ float went[4];
  if (lane == 0) went[wv] = ent;
  __syncthreads();
  if (t == 0) bent[blockIdx.x] = went[0] + went[1] + went[2] + went[3];
}

// ---------------- x -> bf16 cast (same layout) ----------------
__global__ void k_xbf(const float* __restrict__ x, ushort* __restrict__ xbf) {
  size_t i = (size_t)(blockIdx.x * 256 + threadIdx.x) * 4;
  float4 v = *(const float4*)&x[i];
  ushort4 o;
  o.x = f2bf(v.x); o.y = f2bf(v.y); o.z = f2bf(v.z); o.w = f2bf(v.w);
  *(ushort4*)&xbf[i] = o;
}

// ---------------- transpose sbf[n][k] -> STbf[k][n] (bf16) ----------------
__global__ void k_transpose(const ushort* __restrict__ sbf, ushort* __restrict__ STbf) {
  __shared__ ushort lds[64 * 65];
  int t = threadIdx.x;
  int ktile = blockIdx.x & 15, nt = blockIdx.x >> 4;
  int n0 = nt * 64, k0 = ktile * 64;
#pragma unroll
  for (int p = 0; p < 2; ++p) {
    int row = p * 32 + (t >> 3);
    int c8 = (t & 7) * 8;
    uint4 v = *(const uint4*)&sbf[(size_t)(n0 + row) * KCB + k0 + c8];
    ushort* vp = (ushort*)&v;
#pragma unroll
    for (int j = 0; j < 8; ++j) lds[row * 65 + c8 + j] = vp[j];
  }
  __syncthreads();
#pragma unroll
  for (int p = 0; p < 2; ++p) {
    int krow = p * 32 + (t >> 3);
    int nc8 = (t & 7) * 8;
    ushort tmp[8];
#pragma unroll
    for (int j = 0; j < 8; ++j) tmp[j] = lds[(nc8 + j) * 65 + krow];
    *(uint4*)&STbf[(size_t)(k0 + krow) * NROWS + n0 + nc8] = *(uint4*)tmp;
  }
}

// ---------------- quantized output: out[b,d,h,w] = w[idx[n], d] ----------------
__global__ void k_quant(const float* __restrict__ w, const int* __restrict__ idxArr,
                        float* __restrict__ outQ) {
  int n = blockIdx.x * 256 + threadIdx.x;
  int b = n >> 10, m = n & 1023;
  int id = idxArr[n];
  const float* wr = w + (size_t)id * DDIM;
  float* o = outQ + (size_t)b * DDIM * 1024 + m;
#pragma unroll 4
  for (int d = 0; d < DDIM; ++d) o[(size_t)d * 1024] = wr[d];
}

// ---------------- GEMM2 (MFMA bf16): dw[k,d] = sum_n soft[n,k] x[n,d] ----------------
// A = STbf[k][n], B = xbf[d][n] (both reduction-major). Tile 256k x 128d, NT=64.
// grid = kt(4) x dt(2) x ns(32) = 256 blocks, 512 threads (8 waves: 4k x 2d).
__global__ __launch_bounds__(512) void k_gemm2_mfma(const ushort* __restrict__ STbf,
                                                    const ushort* __restrict__ xbf,
                                                    float* __restrict__ P) {
  __shared__ __align__(16) ushort Abuf[256 * 72];
  __shared__ __align__(16) ushort Bbuf[128 * 72];
  int t = threadIdx.x;
  int bid = blockIdx.x;
  int kt = bid & 3, dt = (bid >> 2) & 1, ns = bid >> 3;
  int k0 = kt * 256, d0 = dt * 128;
  int l = t & 63, wv = t >> 6;
  int wk = wv >> 1, wd = wv & 1;
  f32x4 zero = {0.f, 0.f, 0.f, 0.f};
  f32x4 acc[4][4];
#pragma unroll
  for (int i = 0; i < 4; ++i)
#pragma unroll
    for (int j = 0; j < 4; ++j) acc[i][j] = zero;

  int colv = (t & 7) * 8;
  int rbase = t >> 3;
  for (int s = 0; s < 16; ++s) {
    size_t nb = (size_t)ns * 1024 + s * 64;
#pragma unroll
    for (int p = 0; p < 4; ++p) {
      int row = p * 64 + rbase;
      uint4 v = *(const uint4*)&STbf[(size_t)(k0 + row) * NROWS + nb + colv];
      *(uint4*)&Abuf[row * 72 + colv] = v;
    }
#pragma unroll
    for (int p = 0; p < 2; ++p) {
      int row = p * 64 + rbase;
      uint4 v = *(const uint4*)&xbf[((size_t)ns * DDIM + d0 + row) * 1024 + s * 64 + colv];
      *(uint4*)&Bbuf[row * 72 + colv] = v;
    }
    __syncthreads();
    bf16x8 af[4][2], bfr[4][2];
#pragma unroll
    for (int sub = 0; sub < 4; ++sub)
#pragma unroll
      for (int nb2 = 0; nb2 < 2; ++nb2) {
        af[sub][nb2]  = *(const bf16x8*)&Abuf[(wk * 64 + sub * 16 + (l & 15)) * 72 + nb2 * 32 + (l >> 4) * 8];
        bfr[sub][nb2] = *(const bf16x8*)&Bbuf[(wd * 64 + sub * 16 + (l & 15)) * 72 + nb2 * 32 + (l >> 4) * 8];
      }
#pragma unroll
    for (int nb2 = 0; nb2 < 2; ++nb2)
#pragma unroll
      for (int i = 0; i < 4; ++i)
#pragma unroll
        for (int j = 0; j < 4; ++j)
          acc[i][j] = __builtin_amdgcn_mfma_f32_16x16x32_bf16(af[i][nb2], bfr[j][nb2], acc[i][j], 0, 0, 0);
    __syncthreads();
  }
  float* Pb = P + (size_t)ns * (KCB * DDIM);
#pragma unroll
  for (int i = 0; i < 4; ++i)
#pragma unroll
    for (int j = 0; j < 4; ++j) {
#pragma unroll
      for (int r = 0; r < 4; ++r) {
        int k = k0 + wk * 64 + i * 16 + (l >> 4) * 4 + r;
        int d = d0 + wd * 64 + j * 16 + (l & 15);
        Pb[(size_t)k * DDIM + d] = acc[i][j][r];
      }
    }
}

// ---------------- colsum[k] = sum_n soft[n][k] (from STbf rows) ----------------
__global__ void k_colsum(const ushort* __restrict__ STbf, float* __restrict__ colsum) {
  int k = blockIdx.x;
  int t = threadIdx.x;
  const ushort* row = STbf + (size_t)k * NROWS;
  float s = 0.f;
#pragma unroll
  for (int c = 0; c < 16; ++c) {
    uint4 v = *(const uint4*)&row[c * 2048 + t * 8];
    ushort* vp = (ushort*)&v;
#pragma unroll
    for (int j = 0; j < 8; ++j) s += bf2f(vp[j]);
  }
  s = wred_sum(s);
  __shared__ float ws4[4];
  if ((t & 63) == 0) ws4[t >> 6] = s;
  __syncthreads();
  if (t == 0) colsum[k] = ws4[0] + ws4[1] + ws4[2] + ws4[3];
}

// ---------------- finalize scalars, new_count ----------------
__global__ void k_final1(const float* __restrict__ ema_count, const float* __restrict__ colsum,
                         const float* __restrict__ hcnt, const float* __restrict__ bent,
                         float* __restrict__ ncnt, float* __restrict__ out) {
  __shared__ float red[1024];
  int t = threadIdx.x;
  const float onem = 1.0f - 0.99f;
  float nc = ema_count[t] * 0.99f + colsum[t] * onem;
  nc = (nc + 1e-5f) / (32768.0f + 1024.0f * 1e-5f) * 32768.0f;
  out[O_NCNT + t] = nc;
  ncnt[t] = nc;
  float s = 0.f;
  for (int i = t; i < 8192; i += 1024) s += bent[i];
  red[t] = s;
  __syncthreads();
  for (int off = 512; off > 0; off >>= 1) { if (t < off) red[t] += red[t + off]; __syncthreads(); }
  if (t == 0) out[O_LOSS] = 0.25f * (red[0] / 32768.0f);
  __syncthreads();
  float avg = hcnt[t] * (1.0f / 32768.0f);
  red[t] = avg * logf(avg + 1e-10f);
  __syncthreads();
  for (int off = 512; off > 0; off >>= 1) { if (t < off) red[t] += red[t + off]; __syncthreads(); }
  if (t == 0) out[O_PERP] = expf(-red[0]);
}

// ---------------- reduce dw partials + new_ema_weight & new_embedding ----------------
__global__ void k_reduce_final2(const float* __restrict__ P, const float* __restrict__ ema_w,
                                const float* __restrict__ ncnt, float* __restrict__ outEW,
                                float* __restrict__ outEMB) {
  int i = blockIdx.x * 256 + threadIdx.x;
  float s = 0.f;
#pragma unroll
  for (int ns = 0; ns < 32; ++ns) s += P[(size_t)ns * (KCB * DDIM) + i];
  float ew = ema_w[i] * 0.99f + s * 0.01f;
  outEW[i] = ew;
  outEMB[i] = ew / ncnt[i >> 8];
}

// ---------------- one-hot encodings (overwrites E scratch) ----------------
__global__ void k_onehot(const int* __restrict__ idxArr, float* __restrict__ E) {
  int gid = blockIdx.x * 256 + threadIdx.x;
  int n = gid >> 8;
  int k4 = (gid & 255) * 4;
  int id = idxArr[n];
  float2* E2 = (float2*)E;
  size_t base = ((size_t)n * KCB + k4) >> 1;
  float2 vA = {(float)(k4 == id), (float)(k4 + 1 == id)};
  float2 vB = {(float)(k4 + 2 == id), (float)(k4 + 3 == id)};
  E2[base] = vA;
  E2[base + 1] = vB;
}

extern "C" void kernel_launch(void* const* d_in, const int* in_sizes, int n_in,
                              void* d_out, int out_size, void* d_ws, size_t ws_size,
                              hipStream_t stream) {
  const float* x = (const float*)d_in[0];
  const float* w = (const float*)d_in[1];
  const float* ema_count = (const float*)d_in[2];
  const float* ema_w = (const float*)d_in[3];
  const float* g = (const float*)d_in[4];
  float* out = (float*)d_out;
  float* ws = (float*)d_ws;

  float* wsq    = ws + W_WSQ;
  float* xsq    = ws + W_XSQ;
  int*   idxArr = (int*)(ws + W_IDX);
  float* colsum = ws + W_COL;
  float* hcnt   = ws + W_HCNT;
  float* bent   = ws + W_BENT;
  float* ncnt   = ws + W_NCNT;
  float* wT     = ws + W_WT;

  float* outQ = out + O_Q;
  float* outE = out + O_ENC;

  // E-region scratch views
  ushort* STbf = (ushort*)(outE + E_STBF);
  ushort* xbf  = (ushort*)(outE + E_XBF);
  float*  P    = outE + E_PART;
  // Q-region scratch view: soft encodings bf16 [N][K] (exact fit 33.55 MB)
  ushort* sbf  = (ushort*)outQ;

  k_init<<<4, 256, 0, stream>>>(hcnt);
  k_wsqT<<<256, 256, 0, stream>>>(w, wsq, wT);
  k_xsq<<<128, 256, 0, stream>>>(x, xsq);
  k_gemm1<<<dim3(8, 256), 256, 0, stream>>>(x, wT, outE);          // S fp32 -> E
  k_rowops<<<8192, 256, 0, stream>>>(outE, g, wsq, xsq, idxArr, hcnt, bent, sbf);
  k_xbf<<<8192, 256, 0, stream>>>(x, xbf);                          // overwrites dead S
  k_transpose<<<8192, 256, 0, stream>>>(sbf, STbf);                 // overwrites dead S
  k_gemm2_mfma<<<256, 512, 0, stream>>>(STbf, xbf, P);
  k_colsum<<<1024, 256, 0, stream>>>(STbf, colsum);
  k_quant<<<128, 256, 0, stream>>>(w, idxArr, outQ);                // overwrites sbf (dead)
  k_final1<<<1, 1024, 0, stream>>>(ema_count, colsum, hcnt, bent, ncnt, out);
  k_reduce_final2<<<1024, 256, 0, stream>>>(P, ema_w, ncnt, out + O_EMAW, out + O_EMB);
  k_onehot<<<32768, 256, 0, stream>>>(idxArr, outE);                // overwrites all E scratch
}

// Round 4
// 443.779 us; speedup vs baseline: 2.0340x; 1.0236x over previous
//
#include <hip/hip_runtime.h>
#include <math.h>

// Problem constants
#define NROWS 32768   // B*H*W
#define KCB   1024    // num embeddings
#define DDIM  256     // embedding dim

// Output offsets (in floats)
#define O_LOSS 0
#define O_Q    1
#define O_PERP 8388609
#define O_ENC  8388610
#define O_NCNT 41943042
#define O_EMAW 41944066
#define O_EMB  42206210

// E-region scratch layout (floats rel. outE; region = 33,554,432 floats exactly)
#define E_XS3   0          // XS3 bf16 [32768][768] (hi|mid|lo) = 12,582,912 floats
#define E_SOFTT 12582912   // softT bf16 [1024][32768] = 16,777,216 floats
#define E_XBF   29360128   // xbf bf16 [32][256][1024] = 4,194,304 floats  (ends 33,554,432)

// Workspace offsets (floats)
#define W_WSQ  0        // 1024
#define W_XSQ  1024     // 32768
#define W_IDX  33792    // 32768 (int)
#define W_COL  66560    // 1024
#define W_HCNT 67584    // 1024
#define W_BENT 68608    // 512
#define W_NCNT 69120    // 1024
#define W_T2V  70144    // 65536
#define W_T2I  135680   // 65536 (int)
#define W_WB   201216   // 1024*768 ushorts = 393216 floats
// total 594,432 floats = 2.38 MB

typedef __attribute__((ext_vector_type(8))) short bf16x8;
typedef __attribute__((ext_vector_type(4))) float f32x4;

__device__ __forceinline__ float wred_sum(float v) {
#pragma unroll
  for (int off = 32; off > 0; off >>= 1) v += __shfl_xor(v, off);
  return v;
}
__device__ __forceinline__ ushort f2bf(float f) {
  union { float f; unsigned u; } c; c.f = f;
  unsigned u = c.u;
  return (ushort)((u + 0x7fffu + ((u >> 16) & 1u)) >> 16);  // RNE
}
__device__ __forceinline__ float bf2f(ushort h) {
  union { unsigned u; float f; } c; c.u = ((unsigned)h) << 16;
  return c.f;
}

// ---------------- init: zero hcnt ----------------
__global__ void k_init(float* __restrict__ hcnt) {
  int i = blockIdx.x * 256 + threadIdx.x;
  if (i < 1024) hcnt[i] = 0.f;
}

// ---------------- w -> wsq + WB [k][768] = [w_hi | w_hi | w_mid] ----------------
__global__ void k_wsplit(const float* __restrict__ w, float* __restrict__ wsq,
                         ushort* __restrict__ WB) {
  int t = threadIdx.x;
  int lane = t & 63, wv = t >> 6;
  int k = blockIdx.x * 4 + wv;
  int d0 = lane * 4;
  float4 v = *(const float4*)&w[(size_t)k * DDIM + d0];
  float s = v.x * v.x + v.y * v.y + v.z * v.z + v.w * v.w;
  s = wred_sum(s);
  if (lane == 0) wsq[k] = s;
  float vv[4] = {v.x, v.y, v.z, v.w};
  union { ushort u[4]; uint2 q; } hh, mm;
#pragma unroll
  for (int q = 0; q < 4; ++q) {
    ushort h = f2bf(vv[q]);
    float r = vv[q] - bf2f(h);
    hh.u[q] = h;
    mm.u[q] = f2bf(r);
  }
  ushort* row = WB + (size_t)k * 768;
  *(uint2*)&row[d0] = hh.q;
  *(uint2*)&row[256 + d0] = hh.q;
  *(uint2*)&row[512 + d0] = mm.q;
}

// ---------------- x -> XS3 (3-way bf16 split, row-major) + xbf (d-major bf16) + xsq ----------------
__global__ __launch_bounds__(256) void k_xsplit(const float* __restrict__ x,
                                                ushort* __restrict__ XS3,
                                                ushort* __restrict__ xbf,
                                                float* __restrict__ xsq) {
  __shared__ __align__(16) ushort sl[32 * 776];
  __shared__ float sq[32 * 9];
  int t = threadIdx.x;
  int b = blockIdx.x >> 5, mt = blockIdx.x & 31;
  int m0 = mt * 32, mloc = t & 31, dgrp = t >> 5;
  const float* xb = x + (size_t)b * DDIM * 1024 + m0 + mloc;
  float s = 0.f;
#pragma unroll
  for (int jj = 0; jj < 8; ++jj) {
    int d0 = dgrp * 32 + jj * 4;
    float vv[4];
#pragma unroll
    for (int q = 0; q < 4; ++q) vv[q] = xb[(size_t)(d0 + q) * 1024];
    union { ushort u[4]; uint2 q; } hh, mi, lo;
#pragma unroll
    for (int q = 0; q < 4; ++q) {
      float v = vv[q];
      ushort h = f2bf(v);
      float r1 = v - bf2f(h);
      ushort m_ = f2bf(r1);
      float r2 = r1 - bf2f(m_);
      hh.u[q] = h; mi.u[q] = m_; lo.u[q] = f2bf(r2);
      s = fmaf(v, v, s);
    }
    int base = mloc * 776;
    *(uint2*)&sl[base + d0] = hh.q;
    *(uint2*)&sl[base + 256 + d0] = mi.q;
    *(uint2*)&sl[base + 512 + d0] = lo.q;
#pragma unroll
    for (int q = 0; q < 4; ++q)
      xbf[(size_t)(b * DDIM + d0 + q) * 1024 + m0 + mloc] = hh.u[q];
  }
  sq[mloc * 9 + dgrp] = s;
  __syncthreads();
  if (t < 32) {
    float ss = 0.f;
#pragma unroll
    for (int gq = 0; gq < 8; ++gq) ss += sq[t * 9 + gq];
    xsq[b * 1024 + m0 + t] = ss;
  }
  ushort* dst = XS3 + (size_t)(b * 1024 + m0) * 768;
#pragma unroll
  for (int p = 0; p < 12; ++p) {
    int idx = p * 256 + t;          // 0..3071 ; 96 x 16B chunks per row
    int row = idx / 96;
    int co = idx - row * 96;
    *(uint4*)&dst[(size_t)row * 768 + co * 8] = *(uint4*)&sl[row * 776 + co * 8];
  }
}

// ---------------- fused GEMM1(MFMA split-bf16) + softmax + top2 + entropy + softT ----------------
// tile 64n x 1024k, K=768 (hi*wh + mid*wh + hi*wm); 512 threads = 8 waves (2n x 4k)
__global__ __launch_bounds__(512) void k_score(const ushort* __restrict__ XS3,
                                               const ushort* __restrict__ WB,
                                               const float* __restrict__ G,
                                               const float* __restrict__ wsq,
                                               const float* __restrict__ xsq,
                                               ushort* __restrict__ softT,
                                               float* __restrict__ bent,
                                               float* __restrict__ t2vg,
                                               int* __restrict__ t2ig) {
  __shared__ __align__(16) ushort shm[43520];  // Bsl[1024*40] | Asl[64*40]; tsl[512*72] aliases
  __shared__ float wsql[1024];
  __shared__ float sxl[64];
  __shared__ float redf[4][64];
  __shared__ float t2v[4][64][2];
  __shared__ int t2i[4][64][2];
  __shared__ float bacc[8];
  ushort* Bsl = shm;
  ushort* Asl = shm + 40960;
  ushort* tsl = shm;

  int t = threadIdx.x;
  int n0 = blockIdx.x * 64;
  int l = t & 63, wid = t >> 6;
  int ng = wid >> 2, kg = wid & 3;
  int c = l & 15, g = l >> 4;

  if (t < 64) sxl[t] = xsq[n0 + t];
  wsql[t] = wsq[t];
  wsql[t + 512] = wsq[t + 512];

  f32x4 zero = {0.f, 0.f, 0.f, 0.f};
  f32x4 acc[2][16];
#pragma unroll
  for (int i = 0; i < 2; ++i)
#pragma unroll
    for (int j = 0; j < 16; ++j) acc[i][j] = zero;

  for (int s = 0; s < 24; ++s) {
    int aoff = ((s >= 8 && s < 16) ? 256 : 0) + (s & 7) * 32;
    int boff = s * 32;
    __syncthreads();
    {
      int row = t >> 3, c4 = (t & 7) * 4;
      *(uint2*)&Asl[row * 40 + c4] = *(const uint2*)&XS3[(size_t)(n0 + row) * 768 + aoff + c4];
    }
    // B tile: 1024 rows x 32 cols bf16 = 4096 uint4 chunks; 8 passes x 512 threads
#pragma unroll
    for (int p = 0; p < 8; ++p) {
      int idx = p * 512 + t;
      int row = idx >> 2, h8 = (idx & 3) * 8;
      *(uint4*)&Bsl[row * 40 + h8] = *(const uint4*)&WB[(size_t)row * 768 + boff + h8];
    }
    __syncthreads();
    bf16x8 aF0 = *(const bf16x8*)&Asl[(ng * 32 + c) * 40 + g * 8];
    bf16x8 aF1 = *(const bf16x8*)&Asl[(ng * 32 + 16 + c) * 40 + g * 8];
#pragma unroll
    for (int j = 0; j < 16; ++j) {
      bf16x8 bF = *(const bf16x8*)&Bsl[(kg * 256 + j * 16 + c) * 40 + g * 8];
      acc[0][j] = __builtin_amdgcn_mfma_f32_16x16x32_bf16(aF0, bF, acc[0][j], 0, 0, 0);
      acc[1][j] = __builtin_amdgcn_mfma_f32_16x16x32_bf16(aF1, bF, acc[1][j], 0, 0, 0);
    }
  }

  // ===== epilogue =====
  // nd = 2*s - xs - wq  (negative distance)
#pragma unroll
  for (int i = 0; i < 2; ++i)
#pragma unroll
    for (int j = 0; j < 16; ++j) {
      float wq = wsql[kg * 256 + j * 16 + c];
#pragma unroll
      for (int r = 0; r < 4; ++r) {
        float xsv = sxl[ng * 32 + i * 16 + g * 4 + r];
        acc[i][j][r] = fmaf(2.f, acc[i][j][r], -(xsv + wq));
      }
    }

  // top-2 of nd+gumbel per row
#pragma unroll
  for (int i = 0; i < 2; ++i)
#pragma unroll
    for (int r = 0; r < 4; ++r) {
      int rowloc = ng * 32 + i * 16 + g * 4 + r;
      const float* Grow = G + (((size_t)(n0 + rowloc)) << 10) + kg * 256 + c;
      float v1 = -3.0e38f, v2 = -3.0e38f;
      int i1 = 0x7fffffff, i2 = 0x7fffffff;
#pragma unroll
      for (int j = 0; j < 16; ++j) {
        float sc = acc[i][j][r] + Grow[j * 16];
        int kk = kg * 256 + j * 16 + c;
        if (sc > v1 || (sc == v1 && kk < i1)) {
          v2 = v1; i2 = i1; v1 = sc; i1 = kk;
        } else if (sc > v2 || (sc == v2 && kk < i2)) {
          v2 = sc; i2 = kk;
        }
      }
#pragma unroll
      for (int off = 1; off < 16; off <<= 1) {
        float ov1 = __shfl_xor(v1, off), ov2 = __shfl_xor(v2, off);
        int oi1 = __shfl_xor(i1, off), oi2 = __shfl_xor(i2, off);
        bool fB = (ov1 > v1) || (ov1 == v1 && oi1 < i1);
        float nv1 = fB ? ov1 : v1; int ni1 = fB ? oi1 : i1;
        float ca = fB ? v1 : ov1;  int cia = fB ? i1 : oi1;
        float cb = fB ? ov2 : v2;  int cib = fB ? oi2 : i2;
        bool sB = (cb > ca) || (cb == ca && cib < cia);
        v1 = nv1; i1 = ni1;
        v2 = sB ? cb : ca; i2 = sB ? cib : cia;
      }
      if (c == 0) {
        t2v[kg][rowloc][0] = v1; t2v[kg][rowloc][1] = v2;
        t2i[kg][rowloc][0] = i1; t2i[kg][rowloc][1] = i2;
      }
    }
  __syncthreads();  // B0
  if (t < 64) {
    float v1 = -3.0e38f, v2 = -3.0e38f;
    int i1 = 0x7fffffff, i2 = 0x7fffffff;
#pragma unroll
    for (int q = 0; q < 4; ++q)
#pragma unroll
      for (int u = 0; u < 2; ++u) {
        float sc = t2v[q][t][u];
        int kk = t2i[q][t][u];
        if (sc > v1 || (sc == v1 && kk < i1)) {
          v2 = v1; i2 = i1; v1 = sc; i1 = kk;
        } else if (sc > v2 || (sc == v2 && kk < i2)) {
          v2 = sc; i2 = kk;
        }
      }
    t2vg[(n0 + t) * 2] = v1; t2vg[(n0 + t) * 2 + 1] = v2;
    t2ig[(n0 + t) * 2] = i1; t2ig[(n0 + t) * 2 + 1] = i2;
  }

  // row max of nd (logits = 2*nd)
#pragma unroll
  for (int i = 0; i < 2; ++i)
#pragma unroll
    for (int r = 0; r < 4; ++r) {
      int rowloc = ng * 32 + i * 16 + g * 4 + r;
      float m = -3.0e38f;
#pragma unroll
      for (int j = 0; j < 16; ++j) m = fmaxf(m, acc[i][j][r]);
#pragma unroll
      for (int off = 1; off < 16; off <<= 1) m = fmaxf(m, __shfl_xor(m, off));
      if (c == 0) redf[kg][rowloc] = m;
    }
  __syncthreads();  // B1
  if (t < 64)
    sxl[t] = 2.f * fmaxf(fmaxf(redf[0][t], redf[1][t]), fmaxf(redf[2][t], redf[3][t]));
  __syncthreads();  // B2

  float rsum[2][4] = {};
#pragma unroll
  for (int i = 0; i < 2; ++i)
#pragma unroll
    for (int r = 0; r < 4; ++r) {
      float mm = sxl[ng * 32 + i * 16 + g * 4 + r];
#pragma unroll
      for (int j = 0; j < 16; ++j) {
        float e = __expf(fmaf(2.f, acc[i][j][r], -mm));
        acc[i][j][r] = e;
        rsum[i][r] += e;
      }
    }
#pragma unroll
  for (int i = 0; i < 2; ++i)
#pragma unroll
    for (int r = 0; r < 4; ++r) {
      float s = rsum[i][r];
#pragma unroll
      for (int off = 1; off < 16; off <<= 1) s += __shfl_xor(s, off);
      if (c == 0) redf[kg][ng * 32 + i * 16 + g * 4 + r] = s;
    }
  __syncthreads();  // B3
  if (t < 64) sxl[t] = 1.0f / (redf[0][t] + redf[1][t] + redf[2][t] + redf[3][t]);
  __syncthreads();  // B4

  float ent = 0.f;
#pragma unroll
  for (int i = 0; i < 2; ++i)
#pragma unroll
    for (int r = 0; r < 4; ++r) {
      float inv = sxl[ng * 32 + i * 16 + g * 4 + r];
#pragma unroll
      for (int j = 0; j < 16; ++j) {
        float sfv = acc[i][j][r] * inv;
        acc[i][j][r] = sfv;
        ent += sfv * __logf(fmaxf(sfv, 1e-8f));
      }
    }
#pragma unroll
  for (int off = 1; off < 64; off <<= 1) ent += __shfl_xor(ent, off);
  if (l == 0) bacc[wid] = ent;

  // transposed softT write via LDS slab, two k-halves
#pragma unroll
  for (int kh = 0; kh < 2; ++kh) {
    __syncthreads();
    if ((kg >> 1) == kh) {
#pragma unroll
      for (int i = 0; i < 2; ++i)
#pragma unroll
        for (int j = 0; j < 16; ++j)
#pragma unroll
          for (int r = 0; r < 4; ++r)
            tsl[((kg & 1) * 256 + j * 16 + c) * 72 + ng * 32 + i * 16 + g * 4 + r] =
                f2bf(acc[i][j][r]);
    }
    __syncthreads();
#pragma unroll
    for (int p = 0; p < 8; ++p) {
      int idx = p * 512 + t;
      int kloc = idx >> 3, ch = idx & 7;
      *(uint4*)&softT[((size_t)(kh * 512 + kloc)) * NROWS + n0 + ch * 8] =
          *(uint4*)&tsl[kloc * 72 + ch * 8];
    }
  }
  __syncthreads();
  if (t == 0) {
    float s = 0.f;
#pragma unroll
    for (int q = 0; q < 8; ++q) s += bacc[q];
    bent[blockIdx.x] = s;
  }
}

// ---------------- exact argmax refinement of top-2 candidates ----------------
__global__ __launch_bounds__(256) void k_refine(const ushort* __restrict__ XS3,
                                                const float* __restrict__ w,
                                                const float* __restrict__ wsq,
                                                const float* __restrict__ xsq,
                                                const float* __restrict__ G,
                                                const int* __restrict__ t2ig,
                                                int* __restrict__ idxArr,
                                                float* __restrict__ hcnt) {
  int t = threadIdx.x;
  int l = t & 63, wv = t >> 6;
  int base = blockIdx.x * 64 + wv * 16;
  int d0 = l * 4;
  for (int rr = 0; rr < 16; ++rr) {
    int n = base + rr;
    const ushort* p = XS3 + (size_t)n * 768;
    union { uint2 q; ushort u[4]; } ha, ma, la;
    ha.q = *(const uint2*)&p[d0];
    ma.q = *(const uint2*)&p[256 + d0];
    la.q = *(const uint2*)&p[512 + d0];
    float xv[4];
#pragma unroll
    for (int q = 0; q < 4; ++q) xv[q] = bf2f(ha.u[q]) + bf2f(ma.u[q]) + bf2f(la.u[q]);
    float xs = xsq[n];
    int ia = t2ig[n * 2], ib = t2ig[n * 2 + 1];
    float sc[2];
    int ids[2] = {ia, ib};
#pragma unroll
    for (int cdd = 0; cdd < 2; ++cdd) {
      int id = ids[cdd];
      const float* wr = w + (size_t)id * DDIM;
      float4 wv4 = *(const float4*)&wr[d0];
      float d = xv[0] * wv4.x + xv[1] * wv4.y + xv[2] * wv4.z + xv[3] * wv4.w;
      d = wred_sum(d);
      sc[cdd] = fmaf(2.f, d, -xs) - wsq[id] + G[((size_t)n << 10) + id];
    }
    int win = (sc[1] > sc[0] || (sc[1] == sc[0] && ib < ia)) ? ib : ia;
    if (l == 0) {
      idxArr[n] = win;
      atomicAdd(&hcnt[win], 1.f);
    }
  }
}

// ---------------- quantized output: out[b,d,h,w] = w[idx[n], d] ----------------
__global__ void k_quant(const float* __restrict__ w, const int* __restrict__ idxArr,
                        float* __restrict__ outQ) {
  int n = blockIdx.x * 256 + threadIdx.x;
  int b = n >> 10, m = n & 1023;
  int id = idxArr[n];
  const float* wr = w + (size_t)id * DDIM;
  float* o = outQ + (size_t)b * DDIM * 1024 + m;
#pragma unroll 4
  for (int d = 0; d < DDIM; ++d) o[(size_t)d * 1024] = wr[d];
}

// ---------------- GEMM2 (MFMA bf16): dw[k,d] = sum_n soft[n,k] x[n,d] ----------------
// A = softT[k][n], B = xbf[b][d][m] (n = b*1024+m). Tile 256k x 128d, NT=64.
__global__ __launch_bounds__(512) void k_gemm2_mfma(const ushort* __restrict__ STbf,
                                                    const ushort* __restrict__ xbf,
                                                    float* __restrict__ P) {
  __shared__ __align__(16) ushort Abuf[256 * 72];
  __shared__ __align__(16) ushort Bbuf[128 * 72];
  int t = threadIdx.x;
  int bid = blockIdx.x;
  int kt = bid & 3, dt = (bid >> 2) & 1, ns = bid >> 3;
  int k0 = kt * 256, d0 = dt * 128;
  int l = t & 63, wv = t >> 6;
  int wk = wv >> 1, wd = wv & 1;
  f32x4 zero = {0.f, 0.f, 0.f, 0.f};
  f32x4 acc[4][4];
#pragma unroll
  for (int i = 0; i < 4; ++i)
#pragma unroll
    for (int j = 0; j < 4; ++j) acc[i][j] = zero;

  int colv = (t & 7) * 8;
  int rbase = t >> 3;
  for (int s = 0; s < 16; ++s) {
    size_t nb = (size_t)ns * 1024 + s * 64;
#pragma unroll
    for (int p = 0; p < 4; ++p) {
      int row = p * 64 + rbase;
      uint4 v = *(const uint4*)&STbf[(size_t)(k0 + row) * NROWS + nb + colv];
      *(uint4*)&Abuf[row * 72 + colv] = v;
    }
#pragma unroll
    for (int p = 0; p < 2; ++p) {
      int row = p * 64 + rbase;
      uint4 v = *(const uint4*)&xbf[((size_t)ns * DDIM + d0 + row) * 1024 + s * 64 + colv];
      *(uint4*)&Bbuf[row * 72 + colv] = v;
    }
    __syncthreads();
    bf16x8 af[4], bfr[4];
#pragma unroll
    for (int nb2 = 0; nb2 < 2; ++nb2) {
#pragma unroll
      for (int sub = 0; sub < 4; ++sub) {
        af[sub] = *(const bf16x8*)&Abuf[(wk * 64 + sub * 16 + (l & 15)) * 72 + nb2 * 32 + (l >> 4) * 8];
        bfr[sub] = *(const bf16x8*)&Bbuf[(wd * 64 + sub * 16 + (l & 15)) * 72 + nb2 * 32 + (l >> 4) * 8];
      }
#pragma unroll
      for (int i = 0; i < 4; ++i)
#pragma unroll
        for (int j = 0; j < 4; ++j)
          acc[i][j] = __builtin_amdgcn_mfma_f32_16x16x32_bf16(af[i], bfr[j], acc[i][j], 0, 0, 0);
    }
    __syncthreads();
  }
  float* Pb = P + (size_t)ns * (KCB * DDIM);
#pragma unroll
  for (int i = 0; i < 4; ++i)
#pragma unroll
    for (int j = 0; j < 4; ++j) {
#pragma unroll
      for (int r = 0; r < 4; ++r) {
        int k = k0 + wk * 64 + i * 16 + (l >> 4) * 4 + r;
        int d = d0 + wd * 64 + j * 16 + (l & 15);
        Pb[(size_t)k * DDIM + d] = acc[i][j][r];
      }
    }
}

// ---------------- colsum[k] = sum_n soft[n][k] (from softT rows) ----------------
__global__ void k_colsum(const ushort* __restrict__ STbf, float* __restrict__ colsum) {
  int k = blockIdx.x;
  int t = threadIdx.x;
  const ushort* row = STbf + (size_t)k * NROWS;
  float s = 0.f;
#pragma unroll
  for (int cc = 0; cc < 16; ++cc) {
    uint4 v = *(const uint4*)&row[cc * 2048 + t * 8];
    ushort* vp = (ushort*)&v;
#pragma unroll
    for (int j = 0; j < 8; ++j) s += bf2f(vp[j]);
  }
  s = wred_sum(s);
  __shared__ float ws4[4];
  if ((t & 63) == 0) ws4[t >> 6] = s;
  __syncthreads();
  if (t == 0) colsum[k] = ws4[0] + ws4[1] + ws4[2] + ws4[3];
}

// ---------------- finalize scalars, new_count ----------------
__global__ void k_final1(const float* __restrict__ ema_count, const float* __restrict__ colsum,
                         const float* __restrict__ hcnt, const float* __restrict__ bent,
                         float* __restrict__ ncnt, float* __restrict__ out) {
  __shared__ float red[1024];
  int t = threadIdx.x;
  const float onem = 1.0f - 0.99f;
  float nc = ema_count[t] * 0.99f + colsum[t] * onem;
  nc = (nc + 1e-5f) / (32768.0f + 1024.0f * 1e-5f) * 32768.0f;
  out[O_NCNT + t] = nc;
  ncnt[t] = nc;
  float s = 0.f;
  for (int i = t; i < 512; i += 1024) s += bent[i];
  red[t] = s;
  __syncthreads();
  for (int off = 512; off > 0; off >>= 1) { if (t < off) red[t] += red[t + off]; __syncthreads(); }
  if (t == 0) out[O_LOSS] = 0.25f * (red[0] / 32768.0f);
  __syncthreads();
  float avg = hcnt[t] * (1.0f / 32768.0f);
  red[t] = avg * logf(avg + 1e-10f);
  __syncthreads();
  for (int off = 512; off > 0; off >>= 1) { if (t < off) red[t] += red[t + off]; __syncthreads(); }
  if (t == 0) out[O_PERP] = expf(-red[0]);
}

// ---------------- reduce dw partials + new_ema_weight & new_embedding ----------------
__global__ void k_reduce_final2(const float* __restrict__ P, const float* __restrict__ ema_w,
                                const float* __restrict__ ncnt, float* __restrict__ outEW,
                                float* __restrict__ outEMB) {
  int i = blockIdx.x * 256 + threadIdx.x;
  float s = 0.f;
#pragma unroll
  for (int ns = 0; ns < 32; ++ns) s += P[(size_t)ns * (KCB * DDIM) + i];
  float ew = ema_w[i] * 0.99f + s * 0.01f;
  outEW[i] = ew;
  outEMB[i] = ew / ncnt[i >> 8];
}

// ---------------- one-hot encodings (overwrites E scratch) ----------------
__global__ void k_onehot(const int* __restrict__ idxArr, float* __restrict__ E) {
  int gid = blockIdx.x * 256 + threadIdx.x;
  int n = gid >> 8;
  int k4 = (gid & 255) * 4;
  int id = idxArr[n];
  float2* E2 = (float2*)E;
  size_t base = ((size_t)n * KCB + k4) >> 1;
  float2 vA = {(float)(k4 == id), (float)(k4 + 1 == id)};
  float2 vB = {(float)(k4 + 2 == id), (float)(k4 + 3 == id)};
  E2[base] = vA;
  E2[base + 1] = vB;
}

extern "C" void kernel_launch(void* const* d_in, const int* in_sizes, int n_in,
                              void* d_out, int out_size, void* d_ws, size_t ws_size,
                              hipStream_t stream) {
  const float* x = (const float*)d_in[0];
  const float* w = (const float*)d_in[1];
  const float* ema_count = (const float*)d_in[2];
  const float* ema_w = (const float*)d_in[3];
  const float* g = (const float*)d_in[4];
  float* out = (float*)d_out;
  float* ws = (float*)d_ws;

  float* wsq    = ws + W_WSQ;
  float* xsq    = ws + W_XSQ;
  int*   idxArr = (int*)(ws + W_IDX);
  float* colsum = ws + W_COL;
  float* hcnt   = ws + W_HCNT;
  float* bent   = ws + W_BENT;
  float* ncnt   = ws + W_NCNT;
  float* top2v  = ws + W_T2V;
  int*   top2i  = (int*)(ws + W_T2I);
  ushort* WB    = (ushort*)(ws + W_WB);

  float* outQ = out + O_Q;
  float* outE = out + O_ENC;

  ushort* XS3   = (ushort*)(outE + E_XS3);
  ushort* softT = (ushort*)(outE + E_SOFTT);
  ushort* xbf   = (ushort*)(outE + E_XBF);
  float*  P     = outQ;  // Q region scratch for GEMM2 partials (exact fit)

  k_init<<<4, 256, 0, stream>>>(hcnt);
  k_wsplit<<<256, 256, 0, stream>>>(w, wsq, WB);
  k_xsplit<<<1024, 256, 0, stream>>>(x, XS3, xbf, xsq);
  k_score<<<512, 512, 0, stream>>>(XS3, WB, g, wsq, xsq, softT, bent, top2v, top2i);
  k_refine<<<512, 256, 0, stream>>>(XS3, w, wsq, xsq, g, top2i, idxArr, hcnt);
  k_colsum<<<1024, 256, 0, stream>>>(softT, colsum);
  k_gemm2_mfma<<<256, 512, 0, stream>>>(softT, xbf, P);
  k_final1<<<1, 1024, 0, stream>>>(ema_count, colsum, hcnt, bent, ncnt, out);
  k_reduce_final2<<<1024, 256, 0, stream>>>(P, ema_w, ncnt, out + O_EMAW, out + O_EMB);
  k_quant<<<128, 256, 0, stream>>>(w, idxArr, outQ);
  k_onehot<<<32768, 256, 0, stream>>>(idxArr, outE);
}